// Round 10
// baseline (182.190 us; speedup 1.0000x reference)
//
#include <hip/hip_runtime.h>
#include <hip/hip_bf16.h>
#include <math.h>

// B=8, H=W=128, CH=64, OC=64, NCA_C=128, K=3, dils {1,2,4,8}, HID=64
// out: y [8,128,128,64] fp32 (8388608) then c2 [8,64] fp32 (512)
//
// Depthwise conv folded into GEMM1 over 33 positions (center-merged), fp8-e4m3
// (U scaled x256). Round-10: occupancy play.
//  - N-SPLIT: each wave computes 32 of 64 out-channels (acc 32 VGPRs) over a
//    64-px half-row. Block = 128 thr (2 waves), grid 2048 -> 8 blocks/CU,
//    16 waves/CU (was 8). __launch_bounds__(128,4) caps VGPR at 128.
//  - All epilogue tables (Cy/Cx/hc2) precomputed GLOBAL in prep2 -> LDS is just
//    hid (9.2 KB) -> no LDS occupancy cap, no per-block table build.
//  - K-loop: unroll-2 ping-pong (A0/B0, A1/B1) -> zero register copies.
//  - One barrier total (hid N-halves exchange before GEMM2), outside K-loop.
// b = blk&7 -> XCD-local L2.

typedef float  f32x4 __attribute__((ext_vector_type(4)));
typedef short  s16x8 __attribute__((ext_vector_type(8)));
typedef long   i64x2 __attribute__((ext_vector_type(2)));

static __device__ __forceinline__ unsigned short f2bf(float f) {
    __hip_bfloat16 h = __float2bfloat16(f);
    unsigned short u; __builtin_memcpy(&u, &h, 2); return u;
}
static __device__ __forceinline__ unsigned pk4fp8(float f0, float f1, float f2, float f3) {
    int v = 0;
    v = __builtin_amdgcn_cvt_pk_fp8_f32(f0, f1, v, false);
    v = __builtin_amdgcn_cvt_pk_fp8_f32(f2, f3, v, true);
    return (unsigned)v;
}

// xpad layout (fp8): [b][yy(144)][xx(144)][64 B: byte oct*16+kc2*8+j = ch kc2*32+oct*8+j]
#define XROWB  9216
#define XBATCH 1327104
#define USCALE 256.0f

// ---------------- prep1: c2 only (tiny) -------------------------------------
__global__ void prep1(const float* __restrict__ c,
                      const float* __restrict__ Wv, const float* __restrict__ bv,
                      const float* __restrict__ Wo, const float* __restrict__ bo,
                      const float* __restrict__ lng, const float* __restrict__ lnb,
                      float* __restrict__ c2f, float* __restrict__ outc2)
{
    const int b = blockIdx.x, j = threadIdx.x;
    __shared__ float sc[64], sv[64];
    float cj = c[b*64 + j];
    sc[j] = cj; __syncthreads();
    float v = bv[j];
    for (int i = 0; i < 64; ++i) v += sc[i]*Wv[i*64 + j];
    sv[j] = v; __syncthreads();
    float t = bo[j] + cj;
    for (int i = 0; i < 64; ++i) t += sv[i]*Wo[i*64 + j];
    float s = t;
    for (int o = 32; o > 0; o >>= 1) s += __shfl_xor(s, o);
    float m = s * (1.f/64.f);
    float dq = (t - m)*(t - m);
    for (int o = 32; o > 0; o >>= 1) dq += __shfl_xor(dq, o);
    float a = (t - m) / sqrtf(dq*(1.f/64.f) + 1e-5f) * lng[j] + lnb[j];
    float c2 = cj + a;
    c2f[b*64 + j] = c2;
    outc2[b*64 + j] = c2;
}

// ---------------- prep2: xpad + U + W2s + V + hc2g + CyG + CxG --------------
__global__ void prep2(const float* __restrict__ x,  const float* __restrict__ pk,
                      const float* __restrict__ W1, const float* __restrict__ W2,
                      const float* __restrict__ b1, const float* __restrict__ c2f,
                      unsigned char* __restrict__ xp, unsigned char* __restrict__ Uf,
                      unsigned short* __restrict__ W2s, float* __restrict__ V,
                      float* __restrict__ hc2g, float* __restrict__ CyG,
                      float* __restrict__ CxG)
{
    const int blk = blockIdx.x, tid = threadIdx.x;
    if (blk < 512) {
        // convert: one px per thread; byte order oct*16 + kc2*8 + j
        int i = blk*256 + tid;
        int xc = i & 127, y = (i >> 7) & 127, b = i >> 14;
        const float* src = x + (size_t)i*64;
        float4 f[16];
        #pragma unroll
        for (int k = 0; k < 16; ++k) f[k] = *(const float4*)(src + k*4);
        unsigned P[16];
        #pragma unroll
        for (int k = 0; k < 16; ++k) P[k] = pk4fp8(f[k].x, f[k].y, f[k].z, f[k].w);
        unsigned char* d = xp + (size_t)b*XBATCH + (size_t)(y+8)*XROWB + (size_t)(xc+8)*64;
        *(uint4*)(d +  0) = make_uint4(P[0], P[1], P[8],  P[9]);
        *(uint4*)(d + 16) = make_uint4(P[2], P[3], P[10], P[11]);
        *(uint4*)(d + 32) = make_uint4(P[4], P[5], P[12], P[13]);
        *(uint4*)(d + 48) = make_uint4(P[6], P[7], P[14], P[15]);
    } else if (blk < 648) {
        int idx = (blk - 512)*256 + tid;     // [0,34816) pad px
        int b = idx / 4352, r = idx - b*4352;
        int yy, xx;
        if (r < 2304) { int ry = r / 144; xx = r - ry*144; yy = (ry < 8) ? ry : 128 + ry; }
        else { int r2 = r - 2304; yy = 8 + (r2 >> 4); int xi = r2 & 15; xx = (xi < 8) ? xi : 128 + xi; }
        unsigned char* d = xp + (size_t)b*XBATCH + (size_t)yy*XROWB + (size_t)xx*64;
        uint4 z = make_uint4(0,0,0,0);
        *(uint4*)(d) = z; *(uint4*)(d+16) = z; *(uint4*)(d+32) = z; *(uint4*)(d+48) = z;
    } else if (blk < 681) {
        // U frags: idx = (pos*4 + nt)*64 + lane; 16 B (kc2 0 | kc2 1), scaled x256
        int idx = (blk - 648)*256 + tid;     // [0, 8448) = 33*4*64
        if (idx < 8448) {
            int lane = idx & 63, nt = (idx >> 6) & 3, pos = idx >> 8;
            int n  = nt*16 + (lane & 15);
            static constexpr int DI[33] = {3,3,3, 2,2,2, 1,1,1, 0,0,0, -1, 0,0, 1,1, 2,2, 3,3,
                                           0,0,0, 1,1,1, 2,2,2, 3,3,3};
            static constexpr int TT[33] = {0,1,2, 0,1,2, 0,1,2, 0,1,2, 4, 3,5, 3,5, 3,5, 3,5,
                                           6,7,8, 6,7,8, 6,7,8, 6,7,8};
            int di = DI[pos], t = TT[pos];
            float vv[16];
            #pragma unroll
            for (int kc2 = 0; kc2 < 2; ++kc2)
                #pragma unroll
                for (int j = 0; j < 8; ++j) {
                    int ch = kc2*32 + (lane >> 4)*8 + j;
                    float v;
                    if (di < 0) {               // merged center
                        v = W1[ch*64 + n];
                        for (int dd = 0; dd < 4; ++dd)
                            v += pk[(dd*128 + ch)*9 + 4] * W1[((1+dd)*128 + ch)*64 + n];
                    } else {
                        v = pk[(di*128 + ch)*9 + t] * W1[((1+di)*128 + ch)*64 + n];
                    }
                    vv[kc2*8 + j] = v * USCALE;
                }
            uint4 o;
            o.x = pk4fp8(vv[0],  vv[1],  vv[2],  vv[3]);
            o.y = pk4fp8(vv[4],  vv[5],  vv[6],  vv[7]);
            o.z = pk4fp8(vv[8],  vv[9],  vv[10], vv[11]);
            o.w = pk4fp8(vv[12], vv[13], vv[14], vv[15]);
            *(uint4*)(Uf + (size_t)idx*16) = o;
        }
    } else if (blk < 683) {
        int idx = (blk - 681)*256 + tid;     // [0,512)
        int lane = idx & 63, nt = (idx >> 6) & 3, kc2 = (idx >> 8) & 1;
        int n  = nt*16 + (lane & 15);
        int k0 = kc2*32 + (lane >> 4)*8;
        unsigned short e[8];
        #pragma unroll
        for (int j = 0; j < 8; ++j) e[j] = f2bf(W2[(k0+j)*64 + n]);
        uint4 o;
        o.x = (unsigned)e[0] | ((unsigned)e[1] << 16);
        o.y = (unsigned)e[2] | ((unsigned)e[3] << 16);
        o.z = (unsigned)e[4] | ((unsigned)e[5] << 16);
        o.w = (unsigned)e[6] | ((unsigned)e[7] << 16);
        *(uint4*)(W2s + (size_t)idx*8) = o;
    } else if (blk < 755) {
        // V[b][p][n], p = di*9 + t
        int idx = (blk - 683)*256 + tid;     // [0, 18432) = 8*36*64
        int n = idx & 63, q = idx >> 6;
        int p = q % 36, b = q / 36;
        int di = p/9, t = p%9;
        float s = 0.f;
        for (int j = 0; j < 64; ++j)
            s += c2f[b*64 + j] * pk[(di*128 + 64 + j)*9 + t] * W1[((1+di)*128 + 64 + j)*64 + n];
        V[(size_t)q*64 + n] = s;
    } else if (blk < 757) {
        // hc2g[b][n] = b1 + sum_j c2*(W1_id + sum_di sum_taps pk*W1)
        int idx = (blk - 755)*256 + tid;     // [0,512)
        if (idx < 512) {
            int b = idx >> 6, n = idx & 63;
            float s = b1[n];
            for (int j = 0; j < 64; ++j) {
                float wsum = W1[(64 + j)*64 + n];
                for (int di = 0; di < 4; ++di) {
                    float ks = 0.f;
                    for (int t = 0; t < 9; ++t) ks += pk[(di*128 + 64 + j)*9 + t];
                    wsum += ks * W1[((1+di)*128 + 64 + j)*64 + n];
                }
                s += c2f[b*64 + j] * wsum;
            }
            hc2g[idx] = s;
        }
    } else if (blk < 1013) {
        // CyG[b][y][n]: OOB-row correction (zero for interior y)
        int idx = (blk - 757)*256 + tid;     // [0, 65536)
        int n = idx & 63, y = (idx >> 6) & 127, b = idx >> 13;
        float s = 0.f;
        for (int di = 0; di < 4; ++di) {
            int d = 1 << di;
            int dyo = (y < d) ? 0 : ((y >= 128 - d) ? 2 : -1);
            if (dyo >= 0) {
                for (int j = 0; j < 64; ++j) {
                    float pks = pk[(di*128 + 64 + j)*9 + dyo*3 + 0]
                              + pk[(di*128 + 64 + j)*9 + dyo*3 + 1]
                              + pk[(di*128 + 64 + j)*9 + dyo*3 + 2];
                    s += c2f[b*64 + j] * pks * W1[((1+di)*128 + 64 + j)*64 + n];
                }
            }
        }
        CyG[idx] = s;
    } else {
        // CxG[b][xi][n], xi<8 -> x=xi else x=112+xi: OOB-column correction
        int idx = (blk - 1013)*256 + tid;    // [0, 8192)
        int n = idx & 63, xi = (idx >> 6) & 15, b = idx >> 10;
        int xx = (xi < 8) ? xi : 112 + xi;
        float s = 0.f;
        for (int di = 0; di < 4; ++di) {
            int d = 1 << di;
            int dxo = (xx < d) ? 0 : ((xx >= 128 - d) ? 2 : -1);
            if (dxo >= 0) {
                for (int j = 0; j < 64; ++j) {
                    float pks = pk[(di*128 + 64 + j)*9 + 0*3 + dxo]
                              + pk[(di*128 + 64 + j)*9 + 1*3 + dxo]
                              + pk[(di*128 + 64 + j)*9 + 2*3 + dxo];
                    s += c2f[b*64 + j] * pks * W1[((1+di)*128 + 64 + j)*64 + n];
                }
            }
        }
        CxG[idx] = s;
    }
}

// ---------------- main fused kernel -----------------------------------------
#define HID_S 72

__global__ __launch_bounds__(128, 4) void nca_main(
    const unsigned char* __restrict__ xp,
    const unsigned char* __restrict__ U,
    const unsigned short* __restrict__ W2s,
    const float* __restrict__ V,
    const float* __restrict__ hc2g,
    const float* __restrict__ CyG,
    const float* __restrict__ CxG,
    const float* __restrict__ b2,
    float* __restrict__ out)
{
    __shared__ unsigned short hid[64*HID_S];   // 9216 B only

    const int tid = threadIdx.x;
    const int blk = blockIdx.x;
    const int b  = blk & 7;                    // XCD-local batch
    const int q  = blk >> 3;                   // [0,256)
    const int y  = q >> 1;
    const int xw = (q & 1) * 64;

    const int lane = tid & 63;
    const int w    = tid >> 6;                 // N-half: nt in {2w, 2w+1}
    const int ln15 = lane & 15;
    const int oct  = lane >> 4;

    const unsigned char* abase = xp + (size_t)b*XBATCH + (size_t)(y + 8)*XROWB
                               + (size_t)(xw + ln15 + 8)*64 + oct*16;
    const unsigned char* ubase = U + (size_t)w*2048 + (size_t)lane*16;

    f32x4 acc[4][2];
    #pragma unroll
    for (int mt = 0; mt < 4; ++mt)
        #pragma unroll
        for (int j = 0; j < 2; ++j) {
            acc[mt][j][0] = 0.f; acc[mt][j][1] = 0.f;
            acc[mt][j][2] = 0.f; acc[mt][j][3] = 0.f;
        }

    static constexpr int OFF[33] = {
        (-8*144-8)*64, (-8*144)*64, (-8*144+8)*64,
        (-4*144-4)*64, (-4*144)*64, (-4*144+4)*64,
        (-2*144-2)*64, (-2*144)*64, (-2*144+2)*64,
        (-1*144-1)*64, (-1*144)*64, (-1*144+1)*64,
        0,
        -64, 64, -128, 128, -256, 256, -512, 512,
        ( 1*144-1)*64, ( 1*144)*64, ( 1*144+1)*64,
        ( 2*144-2)*64, ( 2*144)*64, ( 2*144+2)*64,
        ( 4*144-4)*64, ( 4*144)*64, ( 4*144+4)*64,
        ( 8*144-8)*64, ( 8*144)*64, ( 8*144+8)*64
    };

    i64x2 A0[4], A1[4], B0[2], B1[2];
    auto loadA = [&](i64x2* A, int pos) {
        const unsigned char* rp = abase + OFF[pos];
        #pragma unroll
        for (int mt = 0; mt < 4; ++mt) A[mt] = *(const i64x2*)(rp + mt*1024);
    };
    auto loadB = [&](i64x2* Bv, int pos) {
        const unsigned char* up = ubase + (size_t)pos*4096;
        Bv[0] = *(const i64x2*)(up);
        Bv[1] = *(const i64x2*)(up + 1024);
    };
    auto mfblk = [&](i64x2* A, i64x2* Bv) {
        #pragma unroll
        for (int kc2 = 0; kc2 < 2; ++kc2)
            #pragma unroll
            for (int j = 0; j < 2; ++j) {
                long bf = Bv[j][kc2];
                #pragma unroll
                for (int mt = 0; mt < 4; ++mt)
                    acc[mt][j] = __builtin_amdgcn_mfma_f32_16x16x32_fp8_fp8(A[mt][kc2], bf, acc[mt][j], 0, 0, 0);
            }
    };

    loadA(A0, 0);  loadB(B0, 0);
    loadA(A1, 1);  loadB(B1, 1);

    // ping-pong, zero copies: even pos in buf0, odd in buf1
    #pragma unroll 1
    for (int i = 0; i < 16; ++i) {
        mfblk(A0, B0);
        int pa = 2*i + 2;                       // <= 32
        loadA(A0, pa); loadB(B0, pa);
        mfblk(A1, B1);
        int pb = (2*i + 3 <= 32) ? (2*i + 3) : 32;
        loadA(A1, pb); loadB(B1, pb);
    }
    mfblk(A0, B0);                              // pos 32

    // ---- epilogue 1: acc/256 + hc2 - Cy - Cx (+corner), GELU, hid ----
    const bool yedge = (y < 8) || (y >= 120);
    #pragma unroll
    for (int j = 0; j < 2; ++j) {
        const int n = (w*2 + j)*16 + ln15;
        const float h0 = hc2g[b*64 + n] - CyG[((b << 7) + y)*64 + n];
        #pragma unroll
        for (int mt = 0; mt < 4; ++mt) {
            #pragma unroll
            for (int r = 0; r < 4; ++r) {
                int m = mt*16 + oct*4 + r;      // local px [0,64)
                int x = xw + m;
                float h = acc[mt][j][r]*(1.0f/USCALE) + h0;
                if (x < 8 || x >= 120) {
                    int xi = (x < 8) ? x : (x - 112);
                    h -= CxG[((b << 4) + xi)*64 + n];
                    if (yedge) {                // corner double-subtract fix
                        #pragma unroll
                        for (int di = 0; di < 4; ++di) {
                            int d = 1 << di;
                            int dyo = (y < d) ? 0 : ((y >= 128 - d) ? 2 : -1);
                            int dxo = (x < d) ? 0 : ((x >= 128 - d) ? 2 : -1);
                            if (dyo >= 0 && dxo >= 0)
                                h += V[((size_t)b*36 + di*9 + dyo*3 + dxo)*64 + n];
                        }
                    }
                }
                float u = 0.7978845608028654f * (h + 0.044715f*h*h*h);
                float g = h / (1.f + __expf(-2.f*u));
                hid[m*HID_S + n] = f2bf(g);
            }
        }
    }
    __syncthreads();   // exchange N-halves of hid between the 2 waves

    // ---- GEMM2: y = hid @ W2 + b2 (bf16), wave computes its N-half ----
    f32x4 acc2[4][2];
    #pragma unroll
    for (int mt = 0; mt < 4; ++mt)
        #pragma unroll
        for (int j = 0; j < 2; ++j) {
            acc2[mt][j][0] = 0.f; acc2[mt][j][1] = 0.f;
            acc2[mt][j][2] = 0.f; acc2[mt][j][3] = 0.f;
        }
    #pragma unroll
    for (int kc2 = 0; kc2 < 2; ++kc2) {
        s16x8 a2[4];
        #pragma unroll
        for (int mt = 0; mt < 4; ++mt)
            a2[mt] = *(const s16x8*)&hid[(mt*16 + ln15)*HID_S + kc2*32 + oct*8];
        #pragma unroll
        for (int j = 0; j < 2; ++j) {
            int nt = w*2 + j;
            s16x8 bf = *(const s16x8*)(W2s + ((size_t)(kc2*4 + nt)*64 + lane)*8);
            #pragma unroll
            for (int mt = 0; mt < 4; ++mt)
                acc2[mt][j] = __builtin_amdgcn_mfma_f32_16x16x32_bf16(a2[mt], bf, acc2[mt][j], 0, 0, 0);
        }
    }

    float* ob = out + ((size_t)(b*128 + y))*128*64;
    #pragma unroll
    for (int j = 0; j < 2; ++j) {
        const int n = (w*2 + j)*16 + ln15;
        const float b2v = b2[n];
        #pragma unroll
        for (int mt = 0; mt < 4; ++mt) {
            #pragma unroll
            for (int r = 0; r < 4; ++r) {
                int x = xw + mt*16 + oct*4 + r;
                ob[(size_t)x*64 + n] = acc2[mt][j][r] + b2v;
            }
        }
    }
}

// ---------------- launch ----------------------------------------------------
extern "C" void kernel_launch(void* const* d_in, const int* in_sizes, int n_in,
                              void* d_out, int out_size, void* d_ws, size_t ws_size,
                              hipStream_t stream) {
    const float* x   = (const float*)d_in[0];
    const float* c   = (const float*)d_in[1];
    // d_in[2..5] = Wq,bq,Wk,bk : unused (softmax weights sum to 1 -> pool == v)
    const float* Wv  = (const float*)d_in[6];
    const float* bv  = (const float*)d_in[7];
    const float* Wo  = (const float*)d_in[8];
    const float* bo  = (const float*)d_in[9];
    const float* lng = (const float*)d_in[10];
    const float* lnb = (const float*)d_in[11];
    const float* pk  = (const float*)d_in[12];
    const float* W1  = (const float*)d_in[13];
    const float* b1  = (const float*)d_in[14];
    const float* W2  = (const float*)d_in[15];
    const float* b2  = (const float*)d_in[16];
    float* out = (float*)d_out;

    char* w = (char*)d_ws;
    unsigned char*  xpb  = (unsigned char*)(w);                  // 10,616,832 B
    unsigned char*  Uf   = (unsigned char*)(w + 10616832);       //    135,168 B
    unsigned short* W2s  = (unsigned short*)(w + 10752000);      //      8,192 B
    float*          V    = (float*)         (w + 10760192);      //     73,728 B
    float*          hc2g = (float*)         (w + 10833920);      //      2,048 B
    float*          c2f  = (float*)         (w + 10835968);      //      2,048 B
    float*          CyG  = (float*)         (w + 10838016);      //    262,144 B
    float*          CxG  = (float*)         (w + 11100160);      //     32,768 B (end 11,132,928)

    prep1<<<8, 64, 0, stream>>>(c, Wv, bv, Wo, bo, lng, lnb, c2f, out + 8388608);
    prep2<<<1045, 256, 0, stream>>>(x, pk, W1, W2, b1, c2f, xpb, Uf, W2s, V, hc2g, CyG, CxG);
    nca_main<<<2048, 128, 0, stream>>>(xpb, Uf, W2s, V, hc2g, CyG, CxG, b2, out);
}